// Round 4
// baseline (100.233 us; speedup 1.0000x reference)
//
#include <hip/hip_runtime.h>
#include <hip/hip_bf16.h>

// Chamfer, B=4, N=M=8192 fp32 -> scalar. Round 4:
//  - fuse Q premultiply into the min kernel's LDS staging (prep dispatch eliminated)
//  - wmin init via hipMemsetAsync(0xFF): uint-ordered atomicMin treats 0xFFFFFFFF as +inf
//  - P kept raw (|p|^2 recomputed in epilogue) -> 8 fewer live VGPRs, no unscale muls
//  - __launch_bounds__(256,4): allow up to 128 VGPRs so the 3.5-op/pair inner loop
//    actually register-allocates (round 3's 48-VGPR allocation ~doubled the op count)
//  - single-block reduce writes out[0] directly (no atomicAdd, no init dispatch)

#define BATCH 4
#define NPTS 8192
#define MS 32                  // m-chunks per direction
#define RPT 8                  // n-points per thread
#define CHUNK (NPTS / MS)      // 256 q-points per block
#define SETPTS (BATCH * NPTS)  // 32768

__global__ __launch_bounds__(256, 4) void chamfer_min_kernel(
    const float* __restrict__ p1, const float* __restrict__ p2,
    unsigned int* __restrict__ wmin) {
  const int mchunk = blockIdx.x;  // 0..MS-1
  const int nblk = blockIdx.y;    // 0..3
  const int zb = blockIdx.z;      // 0..7
  const int dir = zb >> 2;        // 0: P=p1,Q=p2 ; 1: P=p2,Q=p1
  const int b = zb & 3;
  const float* __restrict__ P = (dir ? p2 : p1) + (size_t)b * NPTS * 3;
  const float* __restrict__ Q = (dir ? p1 : p2) + (size_t)b * NPTS * 3;
  unsigned int* __restrict__ wm = wmin + ((size_t)dir * BATCH + b) * NPTS;

  const int t = threadIdx.x;

  // stage this block's 256 q points into LDS, premultiplied: (-2x,-2y,-2z,|q|^2)
  __shared__ float4 sQ[CHUNK];
  {
    const float* qp = Q + (size_t)(mchunk * CHUNK + t) * 3;
    const float x = qp[0], y = qp[1], z = qp[2];
    sQ[t] = make_float4(-2.f * x, -2.f * y, -2.f * z, fmaf(x, x, fmaf(y, y, z * z)));
  }

  // P points raw in registers; |p|^2 recomputed at epilogue (saves 8 live VGPRs)
  float px[RPT], py[RPT], pz[RPT], acc[RPT];
#pragma unroll
  for (int r = 0; r < RPT; ++r) {
    const int n = nblk * (RPT * 256) + r * 256 + t;
    const float* pp = P + (size_t)n * 3;
    px[r] = pp[0];
    py[r] = pp[1];
    pz[r] = pp[2];
    acc[r] = INFINITY;  // min over q of (|q|^2 - 2 p.q)
  }
  __syncthreads();

  // ping-pong: two groups of 4 q in flight; c = fmaf(px,-2qx, fmaf(py,-2qy, fmaf(pz,-2qz,|q|^2)))
  float4 qa0 = sQ[0], qa1 = sQ[1], qa2 = sQ[2], qa3 = sQ[3];
  for (int j = 0; j < CHUNK; j += 8) {
    const int jb = (j + 4) & (CHUNK - 1);
    float4 qb0 = sQ[jb], qb1 = sQ[jb + 1], qb2 = sQ[jb + 2], qb3 = sQ[jb + 3];
#pragma unroll
    for (int r = 0; r < RPT; ++r) {
      const float c0 = fmaf(px[r], qa0.x, fmaf(py[r], qa0.y, fmaf(pz[r], qa0.z, qa0.w)));
      const float c1 = fmaf(px[r], qa1.x, fmaf(py[r], qa1.y, fmaf(pz[r], qa1.z, qa1.w)));
      const float c2 = fmaf(px[r], qa2.x, fmaf(py[r], qa2.y, fmaf(pz[r], qa2.z, qa2.w)));
      const float c3 = fmaf(px[r], qa3.x, fmaf(py[r], qa3.y, fmaf(pz[r], qa3.z, qa3.w)));
      acc[r] = fminf(fminf(acc[r], c0), c1);  // v_min3_f32
      acc[r] = fminf(fminf(acc[r], c2), c3);  // v_min3_f32
    }
    const int ja = (j + 8) & (CHUNK - 1);
    qa0 = sQ[ja]; qa1 = sQ[ja + 1]; qa2 = sQ[ja + 2]; qa3 = sQ[ja + 3];
#pragma unroll
    for (int r = 0; r < RPT; ++r) {
      const float c0 = fmaf(px[r], qb0.x, fmaf(py[r], qb0.y, fmaf(pz[r], qb0.z, qb0.w)));
      const float c1 = fmaf(px[r], qb1.x, fmaf(py[r], qb1.y, fmaf(pz[r], qb1.z, qb1.w)));
      const float c2 = fmaf(px[r], qb2.x, fmaf(py[r], qb2.y, fmaf(pz[r], qb2.z, qb2.w)));
      const float c3 = fmaf(px[r], qb3.x, fmaf(py[r], qb3.y, fmaf(pz[r], qb3.z, qb3.w)));
      acc[r] = fminf(fminf(acc[r], c0), c1);
      acc[r] = fminf(fminf(acc[r], c2), c3);
    }
  }

#pragma unroll
  for (int r = 0; r < RPT; ++r) {
    const int n = nblk * (RPT * 256) + r * 256 + t;
    const float pw = fmaf(px[r], px[r], fmaf(py[r], py[r], pz[r] * pz[r]));
    const float v = fmaxf(acc[r] + pw, 0.f);  // clamp keeps uint-ordered atomicMin valid
    atomicMin(&wm[n], __float_as_uint(v));
  }
}

__global__ __launch_bounds__(1024) void chamfer_reduce_kernel(
    const float4* __restrict__ wmin4, float* __restrict__ out) {
  // 65536 floats = 16384 float4; one block of 1024 threads, 16 float4 each
  float s = 0.f;
  const int t = threadIdx.x;
#pragma unroll
  for (int k = 0; k < 16; ++k) {
    const float4 v = wmin4[k * 1024 + t];
    s += (v.x + v.y) + (v.z + v.w);
  }
#pragma unroll
  for (int off = 32; off > 0; off >>= 1) s += __shfl_down(s, off, 64);
  __shared__ float wsum[16];
  const int lane = t & 63, wid = t >> 6;
  if (lane == 0) wsum[wid] = s;
  __syncthreads();
  if (t == 0) {
    float tot = 0.f;
#pragma unroll
    for (int w = 0; w < 16; ++w) tot += wsum[w];
    out[0] = tot;
  }
}

extern "C" void kernel_launch(void* const* d_in, const int* in_sizes, int n_in,
                              void* d_out, int out_size, void* d_ws, size_t ws_size,
                              hipStream_t stream) {
  const float* p1 = (const float*)d_in[0];
  const float* p2 = (const float*)d_in[1];
  float* out = (float*)d_out;
  unsigned int* wmin = (unsigned int*)d_ws;  // 2*SETPTS u32 = 256 KB

  // uint-ordered +inf: every clamped (>=0) float bit pattern is < 0xFFFFFFFF
  hipMemsetAsync(wmin, 0xFF, 2 * SETPTS * sizeof(unsigned int), stream);

  dim3 grid(MS, NPTS / (RPT * 256), 2 * BATCH);
  chamfer_min_kernel<<<grid, dim3(256), 0, stream>>>(p1, p2, wmin);

  chamfer_reduce_kernel<<<dim3(1), dim3(1024), 0, stream>>>((const float4*)wmin, out);
}